// Round 1
// baseline (271.658 us; speedup 1.0000x reference)
//
#include <hip/hip_runtime.h>

// ---------------------------------------------------------------------------
// QuantizedShaper: B=256, L=8192, DIM=256, NPAT=64, HIST=32, WIN=8, T=1024.
//
// R13: speculative 2-step-lookahead scan. R12's scan was latency-bound at
// ~252 cyc/step (VALUBusy 29%, stall-dominated): per-step serial chain of
// 6 DPP-max + readlane + SGPR broadcast + cndmask. New scheme:
//   h_i = U_i - cnt_{i-2}   (computable 2 winners back)
//   v_i = h_i - onehot(w_{i-1})
//   top-2 stats of h_i: (A,wh1),(B,wh2) -> winner resolution is pure SALU:
//     w_i = (w_{i-1} != wh1) ? wh1 : ((B > A-1) ? wh2 : wh1)
// Two top-2 reduces in flight (stats for step i+2 issued at step i); the
// 64-lane max uses 4 fused-DPP stages + permlane16/32_swap (all-lane result,
// no readlane on the critical path); argmax lanes via off-path ballot+ffs.
// Bitwise-equivalent to R10/R12 decisions (C integer-exact; A-1.0f exact in
// range and identical to R12's vB = vA-1; same tie-free assumption,
// validated absmax 0.0).
// ---------------------------------------------------------------------------

constexpr int Bb = 256, Ll = 8192, DIMc = 256, NPAT = 64, HIST = 32, WINc = 8;
constexpr int Tt = Ll / WINc;   // 1024
constexpr int TC = 32;          // t-chunk
constexpr int NC = Tt / TC;     // 32 chunks
constexpr float CINV = 1.0f / 64.0f;

#define DPP_STAGE(m, ctrl, rmask)                                              \
  (m) = fmaxf((m), __int_as_float(__builtin_amdgcn_update_dpp(                 \
            __float_as_int(m), __float_as_int(m), (ctrl), (rmask), 0xF, false)))

#define DPP_ADDF(s, ctrl, rmask)                                               \
  do {                                                                         \
    int _si = __float_as_int(s);                                               \
    int _ti = __builtin_amdgcn_update_dpp(_si, _si, (ctrl), (rmask), 0xF, false); \
    (s) += __int_as_float(_ti);                                                \
  } while (0)

#if defined(__has_builtin)
#if __has_builtin(__builtin_amdgcn_permlane16_swap)
#define HAVE_PL16 1
#endif
#if __has_builtin(__builtin_amdgcn_permlane32_swap)
#define HAVE_PL32 1
#endif
#endif

// 64-lane max, result in ALL lanes, no readlane on the dependency chain.
__device__ __forceinline__ float wave_max64(float v, int lane) {
  float m = v;
  DPP_STAGE(m, 0xB1, 0xF);   // xor1
  DPP_STAGE(m, 0x4E, 0xF);   // xor2
  DPP_STAGE(m, 0x141, 0xF);  // row_half_mirror -> 8-group max
  DPP_STAGE(m, 0x140, 0xF);  // row_mirror -> 16-row max (row-uniform)
#if defined(HAVE_PL16)
  {
    auto r = __builtin_amdgcn_permlane16_swap(__float_as_int(m),
                                              __float_as_int(m), false, false);
    m = fmaxf(__int_as_float(r[0]), __int_as_float(r[1]));  // 32-half max
  }
#else
  m = fmaxf(m, __int_as_float(
                   __builtin_amdgcn_ds_swizzle(__float_as_int(m), 0x401F)));
#endif
#if defined(HAVE_PL32)
  {
    auto r = __builtin_amdgcn_permlane32_swap(__float_as_int(m),
                                              __float_as_int(m), false, false);
    m = fmaxf(__int_as_float(r[0]), __int_as_float(r[1]));  // global max
  }
#else
  m = fmaxf(m, __int_as_float(__builtin_amdgcn_ds_bpermute(
                   ((lane ^ 32) << 2), __float_as_int(m))));
#endif
  return m;
}

// one block per pattern p: W2[p,0..31] + bias2[p]
__global__ __launch_bounds__(256) void precompute_kernel(
    const float* __restrict__ conv_w, const float* __restrict__ conv_b,
    const float* __restrict__ keys_w, float* __restrict__ wsf) {
  __shared__ float part[8][32];
  __shared__ float bred[4];
  const int p = blockIdx.x;
  const int t = threadIdx.x;
  const int h = t & 31, g = t >> 5;
  const float* kwp = keys_w + (size_t)p * DIMc;

  float acc = 0.f;
#pragma unroll
  for (int dd = 0; dd < 32; ++dd) {
    int d = g * 32 + dd;
    acc = fmaf(kwp[d], conv_w[d * HIST + h], acc);
  }
  part[g][h] = acc;

  float bp = kwp[t] * conv_b[t];
#pragma unroll
  for (int off = 32; off; off >>= 1) bp += __shfl_down(bp, off);
  if ((t & 63) == 0) bred[t >> 6] = bp;
  __syncthreads();

  if (t < 32) {
    float s = 0.f;
#pragma unroll
    for (int gg = 0; gg < 8; ++gg) s += part[gg][t];
    wsf[(t >> 2) * (NPAT * 4) + p * 4 + (t & 3)] = s;  // float4-friendly
  } else if (t == 32) {
    wsf[NPAT * HIST + p] = (bred[0] + bred[1]) + (bred[2] + bred[3]);
  }
}

__global__ __launch_bounds__(256) void shaper_kernel(
    const float* __restrict__ x, const float* __restrict__ avg_init,
    const float* __restrict__ shapes_w, const float* __restrict__ wsf,
    float* __restrict__ out) {
  __shared__ __align__(16) float xpad[HIST - 1 + Ll + 1];
  __shared__ float scb[2][TC * NPAT];
  __shared__ unsigned long long idxp[NC * 4];  // 8 winners per u64
  __shared__ float shp[WINc * NPAT];

  const int b    = blockIdx.x;
  const int tid  = threadIdx.x;
  const int wid  = tid >> 6;
  const int lane = tid & 63;
  const float* xrow = x + (size_t)b * Ll;

  // ---- stage x (left-padded) + shapes into LDS ----
  if (tid < HIST - 1) xpad[tid] = 0.f;
  {
    const float4* xv4 = (const float4*)xrow;
#pragma unroll
    for (int k = 0; k < 8; ++k) {
      int i4 = k * 256 + tid;
      float4 v = xv4[i4];
      float* dst = xpad + HIST - 1 + i4 * 4;
      dst[0] = v.x; dst[1] = v.y; dst[2] = v.z; dst[3] = v.w;
    }
  }
  for (int i = tid; i < WINc * NPAT; i += 256) shp[i] = shapes_w[i];

  // ---- av0 via DPP-sum butterfly (all waves; validated R5/R8/R10) ----
  float av0;
  {
    float s = avg_init[(size_t)b * NPAT + lane];
    float t = s;
    DPP_ADDF(t, 0xB1, 0xF);
    DPP_ADDF(t, 0x4E, 0xF);
    DPP_ADDF(t, 0x141, 0xF);
    DPP_ADDF(t, 0x140, 0xF);
    DPP_ADDF(t, 0x142, 0xA);
    DPP_ADDF(t, 0x143, 0xC);   // lane63 = total
    float tot = __int_as_float(__builtin_amdgcn_readlane(__float_as_int(t), 63));
    av0 = s - tot * CINV;
  }

  // ---- per-role setup ----
  float4 w2v[8];
  float  b2 = 0.f;
  if (wid > 0) {
    const float4* w2g = (const float4*)wsf;
#pragma unroll
    for (int h4 = 0; h4 < 8; ++h4) w2v[h4] = w2g[h4 * 64 + lane];
    b2 = wsf[NPAT * HIST + lane];
  }
  __syncthreads();

  // fill chunk c: sb[t][p] = (relu6(score) - av0[p]) + tglob/64  (== U_t[p])
  auto fill = [&](int c, float* __restrict__ sb) {
    int base = c * TC;
    for (int tl = wid - 1; tl < TC; tl += 3) {
      int t = base + tl;
      const float4* xw = (const float4*)(xpad + t * WINc);  // 32B-aligned
      float acc = b2;
#pragma unroll
      for (int h4 = 0; h4 < 8; ++h4) {
        float4 xv = xw[h4];
        float4 wv = w2v[h4];
        acc = fmaf(xv.x, wv.x, acc);
        acc = fmaf(xv.y, wv.y, acc);
        acc = fmaf(xv.z, wv.z, acc);
        acc = fmaf(xv.w, wv.w, acc);
      }
      float sc = fminf(fmaxf(acc, 0.f), 6.f);
      sb[tl * NPAT + lane] = (sc - av0) + (float)t * CINV;
    }
  };

  // ---- scan state (wave 0): C = win count (starts 0), across chunks ----
  float C = 0.f;
  const float NEGINF = __int_as_float(0xff800000);

  auto scan_chunk = [&](const float* __restrict__ sb, int cidx) {
    float U[TC];
#pragma unroll
    for (int i = 0; i < TC; ++i) U[i] = sb[i * NPAT + lane];

    unsigned long long pk0 = 0, pk1 = 0, pk2 = 0, pk3 = 0;

    // top-2 stats of h: A=max@wh1, B=2nd-max@wh2, gt=(B > A-1)
    auto build_stats = [&](float h, int& wh1o, int& wh2o, bool& gto) {
      float A  = wave_max64(h, lane);
      float hm = (h == A) ? NEGINF : h;
      float Bv = wave_max64(hm, lane);
      wh1o = __ffsll(__ballot(h == A)) - 1;
      wh2o = __ffsll(__ballot(hm == Bv)) - 1;
      gto  = (__ballot(Bv > A - 1.0f) != 0ull);
    };

    int wh1s[2], wh2s[2];
    bool gts[2];

    // ---- prologue: step 0 exact, prime stats for steps 1 (slot1), 2 (slot0)
    float v0 = U[0] - C;
    float h1 = U[1] - C;                 // = U[1] - cnt_{-1}
    float M0 = wave_max64(v0, lane);
    build_stats(h1, wh1s[1], wh2s[1], gts[1]);
    int w = __ffsll(__ballot(v0 == M0)) - 1;
    C += (lane == w) ? 1.0f : 0.0f;      // cnt_0
    pk0 = (unsigned long long)w;
    float h2 = U[2] - C;                 // = U[2] - cnt_0
    build_stats(h2, wh1s[0], wh2s[0], gts[0]);

    // ---- steady loop: resolve step i (SALU), issue stats for step i+2 ----
#pragma unroll
    for (int i = 1; i < TC; ++i) {
      const int p = i & 1;
      bool rep = (w == wh1s[p]);
      int  wi  = rep ? (gts[p] ? wh2s[p] : wh1s[p]) : wh1s[p];
      C += (lane == wi) ? 1.0f : 0.0f;
      w = wi;
      unsigned long long wq = (unsigned long long)w;
      if (i < 8)       pk0 |= wq << (8 * (i & 7));
      else if (i < 16) pk1 |= wq << (8 * (i & 7));
      else if (i < 24) pk2 |= wq << (8 * (i & 7));
      else             pk3 |= wq << (8 * (i & 7));
      if (i + 2 < TC) {
        float h = U[i + 2] - C;          // = U[i+2] - cnt_i
        build_stats(h, wh1s[p], wh2s[p], gts[p]);
      }
    }

    if (lane == 0) {
      idxp[cidx * 4 + 0] = pk0;
      idxp[cidx * 4 + 1] = pk1;
      idxp[cidx * 4 + 2] = pk2;
      idxp[cidx * 4 + 3] = pk3;
    }
  };

  // ---- pipeline: wave0 scans chunk c, waves1-3 fill chunk c+1 ----
  if (wid > 0) fill(0, scb[0]);
  __syncthreads();

  for (int c = 0; c < NC; ++c) {
    if (wid == 0) {
      scan_chunk(scb[c & 1], c);
    } else if (c + 1 < NC) {
      fill(c + 1, scb[(c + 1) & 1]);
    }
    __syncthreads();
  }

  // ---- epilogue: out[b,l] = relu(shapes[l&7, idx[l>>3]] - x[b,l]) ----
  float4* outv = (float4*)(out + (size_t)b * Ll);
#pragma unroll
  for (int k = 0; k < 8; ++k) {
    int i4 = k * 256 + tid;
    int l0 = i4 * 4;
    int t  = l0 >> 3;
    int w0 = l0 & 7;
    int p  = (int)((idxp[t >> 3] >> (8 * (t & 7))) & 63ull);
    float4 o;
    o.x = fmaxf(shp[(w0 + 0) * NPAT + p] - xpad[HIST - 1 + l0 + 0], 0.f);
    o.y = fmaxf(shp[(w0 + 1) * NPAT + p] - xpad[HIST - 1 + l0 + 1], 0.f);
    o.z = fmaxf(shp[(w0 + 2) * NPAT + p] - xpad[HIST - 1 + l0 + 2], 0.f);
    o.w = fmaxf(shp[(w0 + 3) * NPAT + p] - xpad[HIST - 1 + l0 + 3], 0.f);
    outv[i4] = o;
  }
}

extern "C" void kernel_launch(void* const* d_in, const int* in_sizes, int n_in,
                              void* d_out, int out_size, void* d_ws, size_t ws_size,
                              hipStream_t stream) {
  const float* x        = (const float*)d_in[0];
  const float* avg_init = (const float*)d_in[1];
  const float* conv_w   = (const float*)d_in[2];
  const float* conv_b   = (const float*)d_in[3];
  const float* keys_w   = (const float*)d_in[4];
  const float* shapes_w = (const float*)d_in[5];
  float* wsf = (float*)d_ws;

  precompute_kernel<<<NPAT, 256, 0, stream>>>(conv_w, conv_b, keys_w, wsf);
  shaper_kernel<<<Bb, 256, 0, stream>>>(x, avg_init, shapes_w, wsf,
                                        (float*)d_out);
}

// Round 2
// 164.202 us; speedup vs baseline: 1.6544x; 1.6544x over previous
//
#include <hip/hip_runtime.h>

// ---------------------------------------------------------------------------
// QuantizedShaper: B=256, L=8192, DIM=256, NPAT=64, HIST=32, WIN=8, T=1024.
//
// R14: SALU-free scan loop. R12 (170 us) was latency-bound at ~252 cyc/step;
// R13's speculation regressed (2x serial reduces + per-step ballot/ffs SALU
// round-trips serialize into the in-order issue stream; scan wave is alone
// on its SIMD so every stall is dead time). R14 keeps R12's exact numerics
// and structure but makes the per-step body pure VALU:
//   - all-lane 64-max: 4 fused DPP stages + permlane16_swap + permlane32_swap
//     (validated in R13, absmax 0.0) -> no readlane, no VALU->SALU waits.
//   - winner recording: per-lane VGPR bitmask bm |= e << i (2 VALU ops);
//     ballot/ffs/pack extraction is batched per chunk and done by WAVE 1
//     (fill wave, large slack) from LDS one chunk behind the scan.
// Chain per step: v -> 8-op reduce -> v_cmp -> cndmask (~10 deps, 0 SALU).
// Decisions bitwise-identical to R12: C integer-exact float, vA = U[i+1]-C,
// vB = vA-1 exact, same tie-free e semantics (validated R6-R12).
// ---------------------------------------------------------------------------

constexpr int Bb = 256, Ll = 8192, DIMc = 256, NPAT = 64, HIST = 32, WINc = 8;
constexpr int Tt = Ll / WINc;   // 1024
constexpr int TC = 32;          // t-chunk
constexpr int NC = Tt / TC;     // 32 chunks
constexpr float CINV = 1.0f / 64.0f;

#define DPP_STAGE(m, ctrl, rmask)                                              \
  (m) = fmaxf((m), __int_as_float(__builtin_amdgcn_update_dpp(                 \
            __float_as_int(m), __float_as_int(m), (ctrl), (rmask), 0xF, false)))

#define DPP_ADDF(s, ctrl, rmask)                                               \
  do {                                                                         \
    int _si = __float_as_int(s);                                               \
    int _ti = __builtin_amdgcn_update_dpp(_si, _si, (ctrl), (rmask), 0xF, false); \
    (s) += __int_as_float(_ti);                                                \
  } while (0)

#if defined(__has_builtin)
#if __has_builtin(__builtin_amdgcn_permlane16_swap)
#define HAVE_PL16 1
#endif
#if __has_builtin(__builtin_amdgcn_permlane32_swap)
#define HAVE_PL32 1
#endif
#endif

// 64-lane max, result in ALL lanes, pure VALU (no readlane, no LDS pipe
// when permlane builtins are available). Validated R13 (absmax 0.0).
__device__ __forceinline__ float wave_max64(float v, int lane) {
  float m = v;
  DPP_STAGE(m, 0xB1, 0xF);   // xor1
  DPP_STAGE(m, 0x4E, 0xF);   // xor2
  DPP_STAGE(m, 0x141, 0xF);  // row_half_mirror -> 8-group max
  DPP_STAGE(m, 0x140, 0xF);  // row_mirror -> 16-row max (row-uniform)
#if defined(HAVE_PL16)
  {
    auto r = __builtin_amdgcn_permlane16_swap(__float_as_int(m),
                                              __float_as_int(m), false, false);
    m = fmaxf(__int_as_float(r[0]), __int_as_float(r[1]));  // 32-half max
  }
#else
  m = fmaxf(m, __int_as_float(
                   __builtin_amdgcn_ds_swizzle(__float_as_int(m), 0x401F)));
#endif
#if defined(HAVE_PL32)
  {
    auto r = __builtin_amdgcn_permlane32_swap(__float_as_int(m),
                                              __float_as_int(m), false, false);
    m = fmaxf(__int_as_float(r[0]), __int_as_float(r[1]));  // global max
  }
#else
  m = fmaxf(m, __int_as_float(__builtin_amdgcn_ds_bpermute(
                   ((lane ^ 32) << 2), __float_as_int(m))));
#endif
  return m;
}

// one block per pattern p: W2[p,0..31] + bias2[p]
__global__ __launch_bounds__(256) void precompute_kernel(
    const float* __restrict__ conv_w, const float* __restrict__ conv_b,
    const float* __restrict__ keys_w, float* __restrict__ wsf) {
  __shared__ float part[8][32];
  __shared__ float bred[4];
  const int p = blockIdx.x;
  const int t = threadIdx.x;
  const int h = t & 31, g = t >> 5;
  const float* kwp = keys_w + (size_t)p * DIMc;

  float acc = 0.f;
#pragma unroll
  for (int dd = 0; dd < 32; ++dd) {
    int d = g * 32 + dd;
    acc = fmaf(kwp[d], conv_w[d * HIST + h], acc);
  }
  part[g][h] = acc;

  float bp = kwp[t] * conv_b[t];
#pragma unroll
  for (int off = 32; off; off >>= 1) bp += __shfl_down(bp, off);
  if ((t & 63) == 0) bred[t >> 6] = bp;
  __syncthreads();

  if (t < 32) {
    float s = 0.f;
#pragma unroll
    for (int gg = 0; gg < 8; ++gg) s += part[gg][t];
    wsf[(t >> 2) * (NPAT * 4) + p * 4 + (t & 3)] = s;  // float4-friendly
  } else if (t == 32) {
    wsf[NPAT * HIST + p] = (bred[0] + bred[1]) + (bred[2] + bred[3]);
  }
}

__global__ __launch_bounds__(256) void shaper_kernel(
    const float* __restrict__ x, const float* __restrict__ avg_init,
    const float* __restrict__ shapes_w, const float* __restrict__ wsf,
    float* __restrict__ out) {
  __shared__ __align__(16) float xpad[HIST - 1 + Ll + 1];
  __shared__ float scb[2][TC * NPAT];
  __shared__ unsigned long long idxp[NC * 4];  // 8 winners per u64
  __shared__ unsigned int bmbuf[2][64];        // per-lane win masks, dbuf
  __shared__ float shp[WINc * NPAT];

  const int b    = blockIdx.x;
  const int tid  = threadIdx.x;
  const int wid  = tid >> 6;
  const int lane = tid & 63;
  const float* xrow = x + (size_t)b * Ll;

  // ---- stage x (left-padded) + shapes into LDS ----
  if (tid < HIST - 1) xpad[tid] = 0.f;
  {
    const float4* xv4 = (const float4*)xrow;
#pragma unroll
    for (int k = 0; k < 8; ++k) {
      int i4 = k * 256 + tid;
      float4 v = xv4[i4];
      float* dst = xpad + HIST - 1 + i4 * 4;
      dst[0] = v.x; dst[1] = v.y; dst[2] = v.z; dst[3] = v.w;
    }
  }
  for (int i = tid; i < WINc * NPAT; i += 256) shp[i] = shapes_w[i];

  // ---- av0 via DPP-sum butterfly (all waves; validated R5/R8/R10) ----
  float av0;
  {
    float s = avg_init[(size_t)b * NPAT + lane];
    float t = s;
    DPP_ADDF(t, 0xB1, 0xF);
    DPP_ADDF(t, 0x4E, 0xF);
    DPP_ADDF(t, 0x141, 0xF);
    DPP_ADDF(t, 0x140, 0xF);
    DPP_ADDF(t, 0x142, 0xA);
    DPP_ADDF(t, 0x143, 0xC);   // lane63 = total
    float tot = __int_as_float(__builtin_amdgcn_readlane(__float_as_int(t), 63));
    av0 = s - tot * CINV;
  }

  // ---- per-role setup ----
  float4 w2v[8];
  float  b2 = 0.f;
  if (wid > 0) {
    const float4* w2g = (const float4*)wsf;
#pragma unroll
    for (int h4 = 0; h4 < 8; ++h4) w2v[h4] = w2g[h4 * 64 + lane];
    b2 = wsf[NPAT * HIST + lane];
  }
  __syncthreads();

  // fill chunk c: sb[t][p] = (relu6(score) - av0[p]) + tglob/64  (== U_t[p])
  auto fill = [&](int c, float* __restrict__ sb) {
    int base = c * TC;
    for (int tl = wid - 1; tl < TC; tl += 3) {
      int t = base + tl;
      const float4* xw = (const float4*)(xpad + t * WINc);  // 32B-aligned
      float acc = b2;
#pragma unroll
      for (int h4 = 0; h4 < 8; ++h4) {
        float4 xv = xw[h4];
        float4 wv = w2v[h4];
        acc = fmaf(xv.x, wv.x, acc);
        acc = fmaf(xv.y, wv.y, acc);
        acc = fmaf(xv.z, wv.z, acc);
        acc = fmaf(xv.w, wv.w, acc);
      }
      float sc = fminf(fmaxf(acc, 0.f), 6.f);
      sb[tl * NPAT + lane] = (sc - av0) + (float)t * CINV;
    }
  };

  // ---- scan state (wave 0): C = win count (starts 0), across chunks ----
  float C = 0.f;

  // Pure-VALU scan: no readlane, no ballot, no SALU in the loop. Winners
  // recorded as a per-lane 32-bit mask; extraction happens one chunk later
  // on wave 1.
  auto scan_chunk = [&](const float* __restrict__ sb, int cidx) {
    float U[TC];
#pragma unroll
    for (int i = 0; i < TC; ++i) U[i] = sb[i * NPAT + lane];
    unsigned int bm = 0u;
    float v = U[0] - C;
#pragma unroll
    for (int i = 0; i < TC; ++i) {
      float vA = 0.f, vB = 0.f;
      if (i + 1 < TC) { vA = U[i + 1] - C; vB = vA - 1.0f; }
      float gmax = wave_max64(v, lane);
      bool e = (v == gmax);             // all-maximal (tie-free, R6-R12)
      float C1 = C + 1.0f;
      unsigned int bmn = bm | (1u << i);
      C  = e ? C1 : C;
      bm = e ? bmn : bm;
      if (i + 1 < TC) v = e ? vB : vA;
    }
    bmbuf[cidx & 1][lane] = bm;
  };

  // batched winner extraction for chunk cc (any single wave; uses ballot)
  auto extract = [&](int cc) {
    unsigned int bmv = bmbuf[cc & 1][lane];
    unsigned long long pk0 = 0, pk1 = 0, pk2 = 0, pk3 = 0;
#pragma unroll
    for (int i = 0; i < TC; ++i) {
      unsigned long long mk = __ballot(((bmv >> i) & 1u) != 0u);
      unsigned long long w = (unsigned long long)(__ffsll(mk) - 1);
      if (i < 8)       pk0 |= w << (8 * (i & 7));
      else if (i < 16) pk1 |= w << (8 * (i & 7));
      else if (i < 24) pk2 |= w << (8 * (i & 7));
      else             pk3 |= w << (8 * (i & 7));
    }
    if (lane == 0) {
      idxp[cc * 4 + 0] = pk0;
      idxp[cc * 4 + 1] = pk1;
      idxp[cc * 4 + 2] = pk2;
      idxp[cc * 4 + 3] = pk3;
    }
  };

  // ---- pipeline: wave0 scans chunk c; waves1-3 fill chunk c+1;
  //      wave1 additionally extracts winners of chunk c-1 ----
  if (wid > 0) fill(0, scb[0]);
  __syncthreads();

  for (int c = 0; c < NC; ++c) {
    if (wid == 0) {
      scan_chunk(scb[c & 1], c);
    } else {
      if (c + 1 < NC) fill(c + 1, scb[(c + 1) & 1]);
      if (wid == 1 && c >= 1) extract(c - 1);
    }
    __syncthreads();
  }
  if (wid == 0) extract(NC - 1);
  __syncthreads();

  // ---- epilogue: out[b,l] = relu(shapes[l&7, idx[l>>3]] - x[b,l]) ----
  float4* outv = (float4*)(out + (size_t)b * Ll);
#pragma unroll
  for (int k = 0; k < 8; ++k) {
    int i4 = k * 256 + tid;
    int l0 = i4 * 4;
    int t  = l0 >> 3;
    int w0 = l0 & 7;
    int p  = (int)((idxp[t >> 3] >> (8 * (t & 7))) & 63ull);
    float4 o;
    o.x = fmaxf(shp[(w0 + 0) * NPAT + p] - xpad[HIST - 1 + l0 + 0], 0.f);
    o.y = fmaxf(shp[(w0 + 1) * NPAT + p] - xpad[HIST - 1 + l0 + 1], 0.f);
    o.z = fmaxf(shp[(w0 + 2) * NPAT + p] - xpad[HIST - 1 + l0 + 2], 0.f);
    o.w = fmaxf(shp[(w0 + 3) * NPAT + p] - xpad[HIST - 1 + l0 + 3], 0.f);
    outv[i4] = o;
  }
}

extern "C" void kernel_launch(void* const* d_in, const int* in_sizes, int n_in,
                              void* d_out, int out_size, void* d_ws, size_t ws_size,
                              hipStream_t stream) {
  const float* x        = (const float*)d_in[0];
  const float* avg_init = (const float*)d_in[1];
  const float* conv_w   = (const float*)d_in[2];
  const float* conv_b   = (const float*)d_in[3];
  const float* keys_w   = (const float*)d_in[4];
  const float* shapes_w = (const float*)d_in[5];
  float* wsf = (float*)d_ws;

  precompute_kernel<<<NPAT, 256, 0, stream>>>(conv_w, conv_b, keys_w, wsf);
  shaper_kernel<<<Bb, 256, 0, stream>>>(x, avg_init, shapes_w, wsf,
                                        (float*)d_out);
}